// Round 10
// baseline (229.067 us; speedup 1.0000x reference)
//
#include <hip/hip_runtime.h>
#include <stdint.h>

// Gaussian kernel matrix K[i][j] = exp(-||x_i-x_j||^2/2), X: [16384][64] fp32.
// R10: first TRUE 3-waves/SIMD test. Prepass (R5-proven): Xb = bf16(X),
// nrm[i] = -c*||xb_i||^2. Main kernel loads MFMA-ready bf16 frags (no f32
// staging, no cvt chain) -> ~140 VGPR with a 64x32 wave tile ->
// __launch_bounds__(256,3) fits spill-free (R7 spilled at ~190 VGPR; R5's
// 512-thread blocks could never fit a 2nd block -> occupancy never tested).
// 2-slot B rotation: MFMA(t) waits only on loads(t) issued before stores(t-1)
// => requires only stores(t-2) drained (2 tiles of store-drain slack).
// Store shape kept at proven-saturated 1KB/instr (8 rows x 128B).
// Col norms load directly from nrm as f32x4 (no shfl). Diagonal: uniform
// branch + exact select (norms from same bf16 values MFMA sees).

typedef __attribute__((ext_vector_type(8))) short  s16x8;  // 8 bf16 (MFMA A/B frag)
typedef __attribute__((ext_vector_type(4))) float  f32x4;
typedef __attribute__((ext_vector_type(4))) unsigned short u16x4;

#define DDIM 64
#define JT 8
#define LROW 36   // LDS row stride in floats (32 data + 4 pad; 4-bank rotation)
#define LOG2E      1.4426950408889634f   // 2c
#define HALF_LOG2E 0.7213475204444817f   // c ; K = exp2(-c||i||^2 - c||j||^2 + 2c dot)

// fp32 -> bf16 RNE on the bit pattern.
__device__ inline unsigned short bf16_rne(float x) {
  uint32_t u = __builtin_bit_cast(uint32_t, x);
  uint32_t r = (u + 0x7fffu + ((u >> 16) & 1u));
  return (unsigned short)(r >> 16);
}
__device__ inline float bf16_to_f32(unsigned short h) {
  return __builtin_bit_cast(float, (uint32_t)h << 16);
}

// ---- pre-pass 1: X (f32) -> Xb (bf16), flat coalesced ----
__global__ __launch_bounds__(256) void k_cvt(const float* __restrict__ X,
                                             unsigned short* __restrict__ Xb) {
  int g = blockIdx.x * 256 + threadIdx.x;      // one f32x4 per thread
  f32x4 v = reinterpret_cast<const f32x4*>(X)[g];
  u16x4 h;
  h[0] = bf16_rne(v[0]); h[1] = bf16_rne(v[1]);
  h[2] = bf16_rne(v[2]); h[3] = bf16_rne(v[3]);
  reinterpret_cast<u16x4*>(Xb)[g] = h;
}

// ---- pre-pass 2: premultiplied row norms from the bf16 table ----
__global__ __launch_bounds__(256) void k_norm(const unsigned short* __restrict__ Xb,
                                              float* __restrict__ nrm) {
  int row = blockIdx.x * 256 + threadIdx.x;    // one row per thread
  const s16x8* p = reinterpret_cast<const s16x8*>(Xb + (size_t)row * DDIM);
  float s = 0.f;
#pragma unroll
  for (int k = 0; k < 8; ++k) {
    s16x8 h = p[k];
#pragma unroll
    for (int e = 0; e < 8; ++e) {
      float f = bf16_to_f32((unsigned short)h[e]);
      s += f * f;
    }
  }
  nrm[row] = -HALF_LOG2E * s;
}

// ---- main: block 128 rows x 512-col strip, 4 waves of 64x32, 3 blocks/CU ----
__global__ __launch_bounds__(256, 3) void gauss_main(
    const unsigned short* __restrict__ Xb, const float* __restrict__ nrm,
    float* __restrict__ K, int n) {
  const int lane = threadIdx.x & 63;
  const int wid  = threadIdx.x >> 6;   // 4 waves: 2 (row) x 2 (col)
  const int wr = wid >> 1;             // 0..1
  const int wc = wid & 1;              // 0..1
  const int l15 = lane & 15;
  const int lq  = lane >> 4;           // 0..3
  const int r8  = lane >> 3;           // 0..7 (store-phase row in 8-group)
  const int e8  = lane & 7;            // 0..7 (store-phase col chunk)

  // Per-wave private transpose buffer: 64 rows x LROW floats (wave-synchronous).
  __shared__ float tbuf[4][64 * LROW];
  float* buf = tbuf[wid];

  const int i0     = blockIdx.x * 128 + wr * 64;   // output row base (this wave)
  const int jstrip = blockIdx.y * (64 * JT);       // 512-col strip base

  // ---- A fragments (MFMA-ready bf16) + row norms ----
  s16x8 a[4][2]; float hA[4];
#pragma unroll
  for (int mi = 0; mi < 4; ++mi) {
    const int row = i0 + mi * 16 + l15;
    a[mi][0] = *reinterpret_cast<const s16x8*>(Xb + (size_t)row * DDIM + lq * 8);
    a[mi][1] = *reinterpret_cast<const s16x8*>(Xb + (size_t)row * DDIM + 32 + lq * 8);
    hA[mi] = nrm[row];   // this lane's output row norm (premultiplied by -c)
  }

  // ---- B: 2-slot rotation. hc[slot][ni][r] = -c*norm of col j0+ni*16+lq*4+r ----
  s16x8 b[2][2][2];
  f32x4 hc[2][2];
#define ISSUE_B(slot, jt_)                                                     \
  do {                                                                         \
    const int j0_ = jstrip + (jt_) * 64 + wc * 32;                             \
    _Pragma("unroll") for (int ni = 0; ni < 2; ++ni) {                         \
      const int row_ = j0_ + ni * 16 + l15;                                    \
      b[slot][ni][0] = *reinterpret_cast<const s16x8*>(                        \
          Xb + (size_t)row_ * DDIM + lq * 8);                                  \
      b[slot][ni][1] = *reinterpret_cast<const s16x8*>(                        \
          Xb + (size_t)row_ * DDIM + 32 + lq * 8);                             \
      hc[slot][ni] = *reinterpret_cast<const f32x4*>(                          \
          nrm + j0_ + ni * 16 + lq * 4);                                       \
    }                                                                          \
  } while (0)

  ISSUE_B(0, 0);

#pragma unroll
  for (int jt = 0; jt < JT; ++jt) {
    const int slot = jt & 1;
    const int j0 = jstrip + jt * 64 + wc * 32;   // this wave's 32-col tile base

    // ---- prefetch next tile's B (issued BEFORE this tile's stores) ----
    if (jt + 1 < JT) ISSUE_B(slot ^ 1, jt + 1);
    // Pin VMEM order only: loads above may not sink below the stores below.
    __builtin_amdgcn_sched_barrier(0x1 | 0x2 | 0x4 | 0x8);

    // ---- MFMA, swapped operands: lane's 4 acc regs = 4 consecutive cols.
    //      Waits on loads(slot) [issued before stores(t-1)] => only stores(t-2)
    //      must drain; stores(t-1) stay in flight. ----
    f32x4 acc[4][2] = {};
#pragma unroll
    for (int ks = 0; ks < 2; ++ks)
#pragma unroll
      for (int mi = 0; mi < 4; ++mi)
#pragma unroll
        for (int ni = 0; ni < 2; ++ni)
          acc[mi][ni] = __builtin_amdgcn_mfma_f32_16x16x32_bf16(
              b[slot][ni][ks], a[mi][ks], acc[mi][ni], 0, 0, 0);

    // Does this 64x32 tile touch the diagonal? (uniform branch)
    const bool diag = (i0 < j0 + 32) && (j0 < i0 + 64);

    // ---- epilogue: exp -> LDS (whole 64x32 tile image) ----
#pragma unroll
    for (int mi = 0; mi < 4; ++mi) {
      const int rg = i0 + mi * 16 + l15;
#pragma unroll
      for (int ni = 0; ni < 2; ++ni) {
        const int c0 = j0 + ni * 16 + lq * 4;
        f32x4 v;
        if (diag) {
#pragma unroll
          for (int r = 0; r < 4; ++r) {
            float e = exp2f(hA[mi] + hc[slot][ni][r] + LOG2E * acc[mi][ni][r]);
            v[r] = (rg == c0 + r) ? 1.0f : e;   // exact diagonal
          }
        } else {
#pragma unroll
          for (int r = 0; r < 4; ++r)
            v[r] = exp2f(hA[mi] + hc[slot][ni][r] + LOG2E * acc[mi][ni][r]);
        }
        *reinterpret_cast<f32x4*>(
            buf + (mi * 16 + l15) * LROW + ni * 16 + lq * 4) = v;
      }
    }

    // ---- store phase: 8 instrs, each 8 rows x 128B contiguous (1KB/instr) ----
#pragma unroll
    for (int g = 0; g < 8; ++g) {
      const int row = g * 8 + r8;
      f32x4 t = *reinterpret_cast<const f32x4*>(buf + row * LROW + e8 * 4);
      *reinterpret_cast<f32x4*>(K + (size_t)(i0 + row) * n + j0 + e8 * 4) = t;
    }
  }
#undef ISSUE_B
}

// ================= R9 fallback (used only if ws_size too small) =============
__device__ inline short cvt1(float x, float& sq) {
  uint32_t u = __builtin_bit_cast(uint32_t, x);
  uint32_t r = (u + 0x7fffu + ((u >> 16) & 1u)) & 0xffff0000u;
  float hf = __builtin_bit_cast(float, r);
  sq += hf * hf;
  return (short)(r >> 16);
}
__device__ inline void issue_row(const float* __restrict__ X, int row, int lq,
                                 f32x4 r[4]) {
  const f32x4* p = reinterpret_cast<const f32x4*>(X + (size_t)row * DDIM + lq * 8);
  const f32x4* q = reinterpret_cast<const f32x4*>(X + (size_t)row * DDIM + 32 + lq * 8);
  r[0] = p[0]; r[1] = p[1]; r[2] = q[0]; r[3] = q[1];
}
__device__ inline void cvt_row(const f32x4 r[4], s16x8 h[2], float& hnorm) {
  float s = 0.f;
#pragma unroll
  for (int ks = 0; ks < 2; ++ks) {
    s16x8 hh;
    hh[0] = cvt1(r[2*ks][0], s);   hh[1] = cvt1(r[2*ks][1], s);
    hh[2] = cvt1(r[2*ks][2], s);   hh[3] = cvt1(r[2*ks][3], s);
    hh[4] = cvt1(r[2*ks+1][0], s); hh[5] = cvt1(r[2*ks+1][1], s);
    hh[6] = cvt1(r[2*ks+1][2], s); hh[7] = cvt1(r[2*ks+1][3], s);
    h[ks] = hh;
  }
  s += __shfl_xor(s, 16);
  s += __shfl_xor(s, 32);
  hnorm = -HALF_LOG2E * s;
}
__global__ __launch_bounds__(256, 2) void gauss_gram_kernel(
    const float* __restrict__ X, float* __restrict__ K, int n) {
  const int lane = threadIdx.x & 63;
  const int wid  = threadIdx.x >> 6;
  const int wr = wid >> 1, wc = wid & 1;
  const int l15 = lane & 15, lq = lane >> 4;
  const int e16 = lane & 15, r4 = lane >> 4;
  __shared__ float tbuf[4][64 * 68];
  float* buf = tbuf[wid];
  const int i0 = blockIdx.x * 128 + wr * 64;
  const int jstrip = blockIdx.y * (128 * JT);
  f32x4 araw[4][4];
#pragma unroll
  for (int mi = 0; mi < 4; ++mi) issue_row(X, i0 + mi * 16 + l15, lq, araw[mi]);
  f32x4 braw[4][4];
#pragma unroll
  for (int ni = 0; ni < 4; ++ni)
    issue_row(X, jstrip + wc * 64 + ni * 16 + l15, lq, braw[ni]);
  s16x8 a[4][2]; float hA[4];
#pragma unroll
  for (int mi = 0; mi < 4; ++mi) cvt_row(araw[mi], a[mi], hA[mi]);
#pragma unroll
  for (int jt = 0; jt < JT; ++jt) {
    const int j0 = jstrip + jt * 128 + wc * 64;
    s16x8 b[4][2]; float hcol[4][4];
#pragma unroll
    for (int ni = 0; ni < 4; ++ni) {
      float hB;
      cvt_row(braw[ni], b[ni], hB);
#pragma unroll
      for (int r = 0; r < 4; ++r) hcol[ni][r] = __shfl(hB, lq * 4 + r);
    }
    if (jt + 1 < JT) {
#pragma unroll
      for (int ni = 0; ni < 4; ++ni)
        issue_row(X, jstrip + (jt + 1) * 128 + wc * 64 + ni * 16 + l15, lq, braw[ni]);
    }
    __builtin_amdgcn_sched_barrier(0x1 | 0x2 | 0x4 | 0x8);
    f32x4 acc[4][4] = {};
#pragma unroll
    for (int ks = 0; ks < 2; ++ks)
#pragma unroll
      for (int mi = 0; mi < 4; ++mi)
#pragma unroll
        for (int ni = 0; ni < 4; ++ni)
          acc[mi][ni] = __builtin_amdgcn_mfma_f32_16x16x32_bf16(
              b[ni][ks], a[mi][ks], acc[mi][ni], 0, 0, 0);
#pragma unroll
    for (int mi = 0; mi < 4; ++mi) {
      const int rg = i0 + mi * 16 + l15;
#pragma unroll
      for (int ni = 0; ni < 4; ++ni) {
        const int c0 = j0 + ni * 16 + lq * 4;
        f32x4 v;
#pragma unroll
        for (int r = 0; r < 4; ++r) {
          float arg = fminf(hA[mi] + hcol[ni][r] + LOG2E * acc[mi][ni][r], 0.0f);
          float e = exp2f(arg);
          v[r] = (rg == c0 + r) ? 1.0f : e;
        }
        *reinterpret_cast<f32x4*>(buf + (mi * 16 + l15) * 68 + ni * 16 + lq * 4) = v;
      }
    }
#pragma unroll
    for (int g = 0; g < 16; ++g) {
      const int row = g * 4 + r4;
      f32x4 t = *reinterpret_cast<const f32x4*>(buf + row * 68 + e16 * 4);
      *reinterpret_cast<f32x4*>(K + (size_t)(i0 + row) * n + j0 + e16 * 4) = t;
    }
  }
}
// ============================================================================

extern "C" void kernel_launch(void* const* d_in, const int* in_sizes, int n_in,
                              void* d_out, int out_size, void* d_ws, size_t ws_size,
                              hipStream_t stream) {
  (void)n_in; (void)out_size;
  const float* X = (const float*)d_in[0];
  float* K = (float*)d_out;
  const int n = in_sizes[0] / DDIM;              // 16384
  const size_t need = (size_t)n * DDIM * 2 + (size_t)n * 4;  // Xb + nrm
  if (ws_size >= need) {
    unsigned short* Xb = (unsigned short*)d_ws;
    float* nrm = (float*)((char*)d_ws + (size_t)n * DDIM * 2);
    k_cvt<<<dim3(n * DDIM / 4 / 256), 256, 0, stream>>>(X, Xb);
    k_norm<<<dim3(n / 256), 256, 0, stream>>>(Xb, nrm);
    dim3 grid(n / 128, n / (64 * JT));           // (128, 32)
    gauss_main<<<grid, 256, 0, stream>>>(Xb, nrm, K, n);
  } else {
    dim3 grid(n / 128, n / (128 * JT));
    gauss_gram_kernel<<<grid, 256, 0, stream>>>(X, K, n);
  }
}